// Round 13
// baseline (520.364 us; speedup 1.0000x reference)
//
#include <hip/hip_runtime.h>
#include <hip/hip_bf16.h>
#include <stdint.h>

#define N_EXPERTS 8
#define DIM 2048
#define INTER 1408
#define NGU (2*INTER)          // 2816
#define TOK_E 2048             // tokens per expert
#define TOTAL_TOKENS 16384

typedef __attribute__((ext_vector_type(8))) short short8;
typedef __attribute__((ext_vector_type(4))) float f32x4;

__device__ __forceinline__ unsigned short f2bf(float f) {
    union { float f; unsigned u; } v; v.f = f;
    unsigned r = v.u + 0x7FFF + ((v.u >> 16) & 1);   // RNE
    return (unsigned short)(r >> 16);
}

#define GLOAD16(G, L) __builtin_amdgcn_global_load_lds( \
    (const __attribute__((address_space(1))) void*)(G), \
    (__attribute__((address_space(3))) void*)(L), 16, 0, 0)

// ---------------- prep kernels (R5/R10 form, verified) ----------------

__global__ void convert_x(const float* __restrict__ in, unsigned short* __restrict__ out, int n8) {
    int i = blockIdx.x * blockDim.x + threadIdx.x;
    int stride = gridDim.x * blockDim.x;
    for (; i < n8; i += stride) {
        const float4* p = (const float4*)(in + (size_t)i * 8);
        float4 v0 = p[0], v1 = p[1];
        union { unsigned short u[8]; uint4 q; } o;
        o.u[0]=f2bf(v0.x); o.u[1]=f2bf(v0.y); o.u[2]=f2bf(v0.z); o.u[3]=f2bf(v0.w);
        o.u[4]=f2bf(v1.x); o.u[5]=f2bf(v1.y); o.u[6]=f2bf(v1.z); o.u[7]=f2bf(v1.w);
        *(uint4*)(out + (size_t)i * 8) = o.q;
    }
}

// in: [E][K][N] fp32 -> out: [E][N][K] bf16, 128(K)x32(N) per block, 8B stores.
// permute: geglu grouping, 32-row groups {16 gate, 16 up} per 16 act cols:
//   a = c>>1, up = c&1 -> B' row = ((a>>4)<<5) + (a&15) + (up<<4)
__global__ __launch_bounds__(256)
void transpose_convert(const float* __restrict__ in, unsigned short* __restrict__ out,
                       int K, int N, int permute) {
    __shared__ float tile[32][129];
    const int n0 = blockIdx.x * 32, k0 = blockIdx.y * 128;
    const size_t ein  = (size_t)blockIdx.z * K * N;
    const size_t eout = (size_t)blockIdx.z * N * K;
    const int tc = threadIdx.x & 31;
    const int tr = threadIdx.x >> 5;
    #pragma unroll
    for (int i = 0; i < 16; ++i) {
        int k = tr + i * 8;
        tile[tc][k] = in[ein + (size_t)(k0 + k) * N + n0 + tc];
    }
    __syncthreads();
    const int kg = threadIdx.x & 31;
    const int r0 = threadIdx.x >> 5;
    #pragma unroll
    for (int i = 0; i < 4; ++i) {
        int r = r0 + i * 8;
        int c = n0 + r;
        int dr = c;
        if (permute) {
            int a = c >> 1;
            dr = ((a >> 4) << 5) + (a & 15) + ((c & 1) << 4);
        }
        union { unsigned short u[4]; uint2 q; } o;
        #pragma unroll
        for (int j = 0; j < 4; ++j) o.u[j] = f2bf(tile[r][kg * 4 + j]);
        *(uint2*)(out + eout + (size_t)dr * K + k0 + kg * 4) = o.q;
    }
}

// ---------------- 256x256xBK64 GEMM, R13: 4 waves (1/SIMD), 512-reg budget ----
// 2x2 wave grid, per-wave 128x128 piece, 16x16x32 MFMA, proven swizzle.
// R13 fix over R12 (NaN): stage-half h = PARITY QUARTERS {h, h+2} (rows
// h*64..h*64+63 and 128+h*64..191+h*64), so the quarter a wave reads at step
// qm (rows wm*128+qm*64) has parity qm for EVERY wave -> the ledger's
// "qm=0 needs half0, qm=1 needs half1" holds uniformly (R12 broke for wm=1).
// Windows per K-tile t (buf b=t&1; stages fill the other buf / next tiles):
//  W1: MF(0,0)[a0,b0]; rd a1=A-p1(t);      stg; VMC(4); bar
//  W2: MF(1,0)[a1,b0]; rd b1=B-p1(t);      stg;         bar
//  W3: MF(0,1)[a0,b1];                     stg; VMC(4); bar
//  W4: MF(1,1)[a1,b1]; rd a0,b0=p0(t+1);   stg; VMC(4); bar
// Stage order per pair: SG1..SG8 = A-p0,B-p0,A-p1,B-p1 of tile t+1 (buf b^1),
// then A-p0,B-p0,A-p1,B-p1 of tile t+2 (buf b). Every half is confirmed by a
// VMC(4) >=1 window before its first read (re-verified incl. prologue & tail).
// Registers: acc 256 + frags 128 + addr ~45 < 512 (1 wave/SIMD budget).

#define SB0 __builtin_amdgcn_sched_barrier(0)
#define VMC(N_) asm volatile("s_waitcnt vmcnt(" #N_ ")" ::: "memory")

#define GEMM_PROLOG(LDKC) \
    const int t = threadIdx.x; \
    const int lane = t & 63, wid = t >> 6; \
    const int wm = wid >> 1, wn = wid & 1;            /* 2M x 2N wave grid */ \
    const int l15 = lane & 15; \
    const int rd0 = (lane & 15) * 64 + (((lane >> 4) ^ (lane & 7)) * 8); \
    const int rd1 = (lane & 15) * 64 + ((((lane >> 4) + 4) ^ (lane & 7)) * 8); \
    const size_t goff = (size_t)(t >> 3) * (LDKC) + (size_t)(((t & 7) ^ ((t >> 3) & 7)) * 8); \
    const int ldsw = wid * 512 + lane * 8;

// stage parity-half h of a 256-row panel (quarters h and h+2): 4 gloads x 32 rows
#define STGA(LDKC, bb_, h_, kt_) do { \
    const unsigned short* g_ = gA + (size_t)(h_) * 64 * (LDKC) + (size_t)(kt_) * 64 + goff; \
    unsigned short* l_ = sA + (bb_) * 16384 + (h_) * 4096 + ldsw; \
    GLOAD16(g_, l_);                               GLOAD16(g_ + (size_t)32 * (LDKC), l_ + 2048); \
    GLOAD16(g_ + (size_t)128 * (LDKC), l_ + 8192); GLOAD16(g_ + (size_t)160 * (LDKC), l_ + 10240); \
} while (0)

#define STGB(LDKC, bb_, h_, kt_) do { \
    const unsigned short* g_ = gB + (size_t)(h_) * 64 * (LDKC) + (size_t)(kt_) * 64 + goff; \
    unsigned short* l_ = sB + (bb_) * 16384 + (h_) * 4096 + ldsw; \
    GLOAD16(g_, l_);                               GLOAD16(g_ + (size_t)32 * (LDKC), l_ + 2048); \
    GLOAD16(g_ + (size_t)128 * (LDKC), l_ + 8192); GLOAD16(g_ + (size_t)160 * (LDKC), l_ + 10240); \
} while (0)

// A frags: quarter (wm*2+qm) = rows wm*128 + qm*64; 4 m-frags x 2 k-halves
#define DSA2(bb_, qm_, DST_) do { \
    const unsigned short* p_ = &sA[(bb_) * 16384 + (wm * 128 + (qm_) * 64) * 64]; \
    _Pragma("unroll") for (int m_ = 0; m_ < 4; ++m_) { \
        DST_[m_][0] = *(const short8*)(p_ + m_ * 1024 + rd0); \
        DST_[m_][1] = *(const short8*)(p_ + m_ * 1024 + rd1); } \
} while (0)

#define DSB2(bb_, qn_, DST_) do { \
    const unsigned short* p_ = &sB[(bb_) * 16384 + (wn * 128 + (qn_) * 64) * 64]; \
    _Pragma("unroll") for (int n_ = 0; n_ < 4; ++n_) { \
        DST_[n_][0] = *(const short8*)(p_ + n_ * 1024 + rd0); \
        DST_[n_][1] = *(const short8*)(p_ + n_ * 1024 + rd1); } \
} while (0)

// 32 MFMA per window
#define QMF(qm_, qn_, A_, B_) do { \
    _Pragma("unroll") for (int k_ = 0; k_ < 2; ++k_) { \
        _Pragma("unroll") for (int m_ = 0; m_ < 4; ++m_) { \
            _Pragma("unroll") for (int n_ = 0; n_ < 4; ++n_) { \
                acc[qm_][qn_][m_][n_] = __builtin_amdgcn_mfma_f32_16x16x32_bf16(A_[m_][k_], B_[n_][k_], acc[qm_][qn_][m_][n_], 0, 0, 0); \
            } } } \
} while (0)

// window: MFMA (prev-window frags) first; reads for next window + stage issue
// in the MFMA shadow; counted VMC; barrier.
#define WIN(MF_, DS_, STG_, END_) do { \
    __builtin_amdgcn_s_setprio(1); \
    MF_; \
    __builtin_amdgcn_s_setprio(0); \
    SB0; \
    DS_; \
    STG_; \
    SB0; \
    END_; \
    __builtin_amdgcn_s_barrier(); \
} while (0)

// 8 windows = 2 K-tiles (tile A: buf0, tile B: buf1)
#define ITER(SG1,SG2,SG3,SG4,SG5,SG6,SG7,SG8, E5,E8, DS8) \
    WIN(QMF(0,0,a0,b0), DSA2(0,1,a1),                SG1, VMC(4)); \
    WIN(QMF(1,0,a1,b0), DSB2(0,1,b1),                SG2, );       \
    WIN(QMF(0,1,a0,b1), ,                            SG3, VMC(4)); \
    WIN(QMF(1,1,a1,b1), DSA2(1,0,a0); DSB2(1,0,b0),  SG4, VMC(4)); \
    WIN(QMF(0,0,a0,b0), DSA2(1,1,a1),                SG5, E5);     \
    WIN(QMF(1,0,a1,b0), DSB2(1,1,b1),                SG6, );       \
    WIN(QMF(0,1,a0,b1), ,                            SG7, E8);     \
    WIN(QMF(1,1,a1,b1), DS8,                         SG8, E8);

#define GEMM_PIPE(LDKC, NI_) \
    short8 a0[4][2], a1[4][2], b0[4][2], b1[4][2]; \
    f32x4 acc[2][2][4][4]; \
    _Pragma("unroll") for (int q_ = 0; q_ < 2; ++q_) \
    _Pragma("unroll") for (int r_ = 0; r_ < 2; ++r_) \
    _Pragma("unroll") for (int m_ = 0; m_ < 4; ++m_) \
    _Pragma("unroll") for (int n_ = 0; n_ < 4; ++n_) acc[q_][r_][m_][n_] = (f32x4)0.0f; \
    /* prologue: tile0 p0(A,B), p1(A,B); confirm through A-p1 (B-p1 in flight) */ \
    STGA(LDKC,0,0,0); STGB(LDKC,0,0,0); STGA(LDKC,0,1,0); STGB(LDKC,0,1,0); \
    VMC(4); \
    __builtin_amdgcn_s_barrier(); \
    DSA2(0,0,a0); DSB2(0,0,b0); \
    for (int it = 0; it < (NI_) - 1; ++it) { \
        const int kt0 = 2 * it; \
        ITER(STGA(LDKC,1,0,kt0+1), STGB(LDKC,1,0,kt0+1), STGA(LDKC,1,1,kt0+1), STGB(LDKC,1,1,kt0+1), \
             STGA(LDKC,0,0,kt0+2), STGB(LDKC,0,0,kt0+2), STGA(LDKC,0,1,kt0+2), STGB(LDKC,0,1,kt0+2), \
             VMC(4), VMC(4), DSA2(0,0,a0); DSB2(0,0,b0)) \
    } \
    { /* last pair: stage tile NT-1 only (W1-W4); no W5-W8 stages/reads-ahead */ \
        const int kt0 = 2 * ((NI_) - 1); \
        ITER(STGA(LDKC,1,0,kt0+1), STGB(LDKC,1,0,kt0+1), STGA(LDKC,1,1,kt0+1), STGB(LDKC,1,1,kt0+1), \
             , , , , VMC(0), , ) \
    }

// ---------------- GEMM 1: x @ gate_up^T (permuted) + GEGLU, bf16 act out ----------------

__global__ __launch_bounds__(256, 1)
void gemm_gu(const unsigned short* __restrict__ A,    // x bf16 [16384][2048]
             const unsigned short* __restrict__ Bt,   // [E][2816][2048] permuted-transposed
             const float* __restrict__ probs,         // [16384]
             unsigned short* __restrict__ act) {      // [16384][1408] bf16
    __shared__ unsigned short sA[2 * 16384];
    __shared__ unsigned short sB[2 * 16384];
    GEMM_PROLOG(DIM)
    const int bid = blockIdx.x;           // 704 = 8 experts * (8 tm * 11 tn)
    const int e = bid & 7;                // expert per XCD (T1)
    const int local = bid >> 3;           // [0, 88), tm-fastest
    const int tm = local & 7;
    const int tn = local >> 3;            // [0, 11)
    const unsigned short* gA = A  + (size_t)(e * TOK_E + tm * 256) * DIM;
    const unsigned short* gB = Bt + (size_t)e * NGU * DIM + (size_t)(tn * 256) * DIM;

    GEMM_PIPE(DIM, 16)   // K = 2048 = 32 tiles of 64 = 16 pairs

    // epilogue: wave B'rows = wn*128 + qn*64 + n*16; 32-row groups {16g,16u}
    // pair p: gate = n=2p, up = n=2p+1; act col = tn*128 + wn*64 + qn*32 + p*16 + l15
    const int rgrp = lane >> 4;
    #pragma unroll
    for (int qm = 0; qm < 2; ++qm) {
        #pragma unroll
        for (int qn = 0; qn < 2; ++qn) {
            #pragma unroll
            for (int m = 0; m < 4; ++m) {
                const int row0 = e * TOK_E + tm * 256 + wm * 128 + qm * 64 + m * 16 + rgrp * 4;
                #pragma unroll
                for (int j = 0; j < 4; ++j) {
                    float p = probs[row0 + j];
                    #pragma unroll
                    for (int pr = 0; pr < 2; ++pr) {
                        float g = fminf(acc[qm][qn][m][2 * pr][j], 7.0f);
                        float u = fminf(fmaxf(acc[qm][qn][m][2 * pr + 1][j], -7.0f), 7.0f);
                        float glu = g / (1.0f + __expf(-1.702f * g));
                        float rv = glu * (u + 1.0f) * p;
                        const int acol = tn * 128 + wn * 64 + qn * 32 + pr * 16 + l15;
                        act[(size_t)(row0 + j) * INTER + acol] = f2bf(rv);
                    }
                }
            }
        }
    }
}

// ---------------- GEMM 2: act @ down^T, fp32 out ----------------

__global__ __launch_bounds__(256, 1)
void gemm_down(const unsigned short* __restrict__ A,   // act bf16 [16384][1408]
               const unsigned short* __restrict__ Bt,  // [E][2048][1408]
               float* __restrict__ out) {               // [16384][2048] fp32
    __shared__ unsigned short sA[2 * 16384];
    __shared__ unsigned short sB[2 * 16384];
    GEMM_PROLOG(INTER)
    const int bid = blockIdx.x;           // 512 = 8 experts * (8 tm * 8 tn)
    const int e = bid & 7;
    const int local = bid >> 3;           // [0, 64), tm-fastest
    const int tm = local & 7;
    const int tn = local >> 3;            // [0, 8)
    const unsigned short* gA = A  + (size_t)(e * TOK_E + tm * 256) * INTER;
    const unsigned short* gB = Bt + (size_t)e * DIM * INTER + (size_t)(tn * 256) * INTER;

    GEMM_PIPE(INTER, 11)   // K = 1408 = 22 tiles of 64 = 11 pairs

    const int rgrp = lane >> 4;
    #pragma unroll
    for (int qm = 0; qm < 2; ++qm) {
        #pragma unroll
        for (int qn = 0; qn < 2; ++qn) {
            #pragma unroll
            for (int m = 0; m < 4; ++m) {
                const int row0 = e * TOK_E + tm * 256 + wm * 128 + qm * 64 + m * 16 + rgrp * 4;
                #pragma unroll
                for (int j = 0; j < 4; ++j) {
                    #pragma unroll
                    for (int n = 0; n < 4; ++n) {
                        const int col = tn * 256 + wn * 128 + qn * 64 + n * 16 + l15;
                        out[(size_t)(row0 + j) * DIM + col] = acc[qm][qn][m][n][j];
                    }
                }
            }
        }
    }
}

// ---------------- launcher ----------------

extern "C" void kernel_launch(void* const* d_in, const int* in_sizes, int n_in,
                              void* d_out, int out_size, void* d_ws, size_t ws_size,
                              hipStream_t stream) {
    const float* x     = (const float*)d_in[0];
    const float* probs = (const float*)d_in[1];
    const float* gup   = (const float*)d_in[2];
    const float* dwn   = (const float*)d_in[3];
    float* out = (float*)d_out;

    char* ws = (char*)d_ws;
    const size_t SZ_XB  = (size_t)TOTAL_TOKENS * DIM * 2;      // 67,108,864
    const size_t SZ_GUB = (size_t)N_EXPERTS * NGU * DIM * 2;   // 92,274,688
    const size_t SZ_DWB = (size_t)N_EXPERTS * DIM * INTER * 2; // 46,137,344
    unsigned short* xb   = (unsigned short*)(ws);
    unsigned short* gub  = (unsigned short*)(ws + SZ_XB);
    unsigned short* dwb  = (unsigned short*)(ws + SZ_XB + SZ_GUB);
    unsigned short* actb = (unsigned short*)(ws + SZ_XB + SZ_GUB + SZ_DWB);

    convert_x<<<2048, 256, 0, stream>>>(x, xb, TOTAL_TOKENS * DIM / 8);

    dim3 tg1(NGU / 32, DIM / 128, N_EXPERTS);     // (88, 16, 8)
    transpose_convert<<<tg1, 256, 0, stream>>>(gup, gub, DIM, NGU, 1);
    dim3 tg2(DIM / 32, INTER / 128, N_EXPERTS);   // (64, 11, 8)
    transpose_convert<<<tg2, 256, 0, stream>>>(dwn, dwb, INTER, DIM, 0);

    gemm_gu<<<704, 256, 0, stream>>>(xb, gub, probs, actb);
    gemm_down<<<512, 256, 0, stream>>>(actb, dwb, out);
}

// Round 14
// 392.087 us; speedup vs baseline: 1.3272x; 1.3272x over previous
//
#include <hip/hip_runtime.h>
#include <hip/hip_bf16.h>
#include <stdint.h>

#define N_EXPERTS 8
#define DIM 2048
#define INTER 1408
#define NGU (2*INTER)          // 2816
#define TOK_E 2048             // tokens per expert
#define TOTAL_TOKENS 16384

typedef __attribute__((ext_vector_type(8))) short short8;
typedef __attribute__((ext_vector_type(4))) float f32x4;

__device__ __forceinline__ unsigned short f2bf(float f) {
    union { float f; unsigned u; } v; v.f = f;
    unsigned r = v.u + 0x7FFF + ((v.u >> 16) & 1);   // RNE
    return (unsigned short)(r >> 16);
}

#define GLOAD16(G, L) __builtin_amdgcn_global_load_lds( \
    (const __attribute__((address_space(1))) void*)(G), \
    (__attribute__((address_space(3))) void*)(L), 16, 0, 0)

// ---------------- prep kernels ----------------

__global__ void convert_x(const float* __restrict__ in, unsigned short* __restrict__ out, int n8) {
    int i = blockIdx.x * blockDim.x + threadIdx.x;
    int stride = gridDim.x * blockDim.x;
    for (; i < n8; i += stride) {
        const float4* p = (const float4*)(in + (size_t)i * 8);
        float4 v0 = p[0], v1 = p[1];
        union { unsigned short u[8]; uint4 q; } o;
        o.u[0]=f2bf(v0.x); o.u[1]=f2bf(v0.y); o.u[2]=f2bf(v0.z); o.u[3]=f2bf(v0.w);
        o.u[4]=f2bf(v1.x); o.u[5]=f2bf(v1.y); o.u[6]=f2bf(v1.z); o.u[7]=f2bf(v1.w);
        *(uint4*)(out + (size_t)i * 8) = o.q;
    }
}

// Both weight transposes in one launch (z<8: gate_up w/ permute, z>=8: down).
// Body identical to the verified transpose_convert (128K x 32N, 8B stores).
// permute: geglu grouping, 32-row groups {16 gate, 16 up} per 16 act cols:
//   a = c>>1, up = c&1 -> B' row = ((a>>4)<<5) + (a&15) + (up<<4)
__global__ __launch_bounds__(256)
void transpose_convert2(const float* __restrict__ gup, unsigned short* __restrict__ gub,
                        const float* __restrict__ dwn, unsigned short* __restrict__ dwb) {
    const int z = blockIdx.z;
    const float* in; unsigned short* out; int K, N, permute, e;
    if (z < 8) { in = gup; out = gub; K = DIM;   N = NGU; permute = 1; e = z; }
    else       { in = dwn; out = dwb; K = INTER; N = DIM; permute = 0; e = z - 8; }
    if ((int)blockIdx.x >= N / 32 || (int)blockIdx.y >= K / 128) return;  // uniform
    __shared__ float tile[32][129];
    const int n0 = blockIdx.x * 32, k0 = blockIdx.y * 128;
    const size_t ein  = (size_t)e * K * N;
    const size_t eout = (size_t)e * N * K;
    const int tc = threadIdx.x & 31;
    const int tr = threadIdx.x >> 5;
    #pragma unroll
    for (int i = 0; i < 16; ++i) {
        int k = tr + i * 8;
        tile[tc][k] = in[ein + (size_t)(k0 + k) * N + n0 + tc];
    }
    __syncthreads();
    const int kg = threadIdx.x & 31;
    const int r0 = threadIdx.x >> 5;
    #pragma unroll
    for (int i = 0; i < 4; ++i) {
        int r = r0 + i * 8;
        int c = n0 + r;
        int dr = c;
        if (permute) {
            int a = c >> 1;
            dr = ((a >> 4) << 5) + (a & 15) + ((c & 1) << 4);
        }
        union { unsigned short u[4]; uint2 q; } o;
        #pragma unroll
        for (int j = 0; j < 4; ++j) o.u[j] = f2bf(tile[r][kg * 4 + j]);
        *(uint2*)(out + eout + (size_t)dr * K + k0 + kg * 4) = o.q;
    }
}

// ---------------- 256x256xBK64 GEMM, 2-buffer, 8-phase pipeline (R10, best) ---
// 8 waves (2M x 4N), per-wave 128x64, 16x16x32 MFMA, conflict-free XOR swizzle.
// Window: DS;STG;SB0;lgkm0;END;SB0;barrier;setprio;MFMA(k-outer);setprio;SB0.
// Stage rotation: P1:b1.Ah1(kt+1) P2:b0.Ah0(kt+2) P3:b0.Bh0 P4:b0.Bh1 P5:b0.Ah1
//                 P6:b1.Ah0(kt+3) P7:b1.Bh0 P8:b1.Bh1.   vmcnt(6) @P4 and @P8.
// Measured: 189 us gemm_gu, MfmaUtil 43.3% = ~95% of the serial-window ceiling
// (LDS 750 cyc + MFMA 620 cyc per K-tile per CU -> 45%). Register budget
// (acc 128 AGPR + 116 VGPR) hard-caps occupancy at 2 waves/SIMD, 1 block/CU;
// deeper lookahead variants (R8/R12/R13) all spill or lose latency tolerance.

#define SB0 __builtin_amdgcn_sched_barrier(0)
#define VMC(N_) asm volatile("s_waitcnt vmcnt(" #N_ ")" ::: "memory")
#define LGK8 asm volatile("s_waitcnt lgkmcnt(8)" ::: "memory")

#define GEMM_PROLOG(LDKC) \
    const int t = threadIdx.x; \
    const int lane = t & 63, wid = t >> 6; \
    const int wm = wid >> 2, wn = wid & 3;            /* 2M x 4N wave grid */ \
    const int l15 = lane & 15; \
    const int rd0 = (lane & 15) * 64 + (((lane >> 4) ^ (lane & 7)) * 8); \
    const int rd1 = (lane & 15) * 64 + ((((lane >> 4) + 4) ^ (lane & 7)) * 8); \
    const size_t goff = (size_t)(t >> 3) * (LDKC) + (size_t)(((t & 7) ^ ((t >> 3) & 7)) * 8); \
    const int ldsw = wid * 512 + lane * 8;

#define STGA(LDKC, bb_, h_, kt_) do { \
    const unsigned short* g_ = gA + (size_t)(h_) * 128 * (LDKC) + (size_t)(kt_) * 64 + goff; \
    unsigned short* l_ = sA + (bb_) * 16384 + (h_) * 8192 + ldsw; \
    GLOAD16(g_, l_); GLOAD16(g_ + (size_t)64 * (LDKC), l_ + 4096); \
} while (0)

#define STGB(LDKC, bb_, h_, kt_) do { \
    const unsigned short* g_ = gB + (size_t)(h_) * 128 * (LDKC) + (size_t)(kt_) * 64 + goff; \
    unsigned short* l_ = sB + (bb_) * 16384 + (h_) * 8192 + ldsw; \
    GLOAD16(g_, l_); GLOAD16(g_ + (size_t)64 * (LDKC), l_ + 4096); \
} while (0)

#define DSA2(bb_, qm_) do { \
    const unsigned short* p_ = &sA[(bb_) * 16384 + ((qm_) * 128 + wm * 64) * 64]; \
    _Pragma("unroll") for (int m_ = 0; m_ < 4; ++m_) { \
        a[m_][0] = *(const short8*)(p_ + m_ * 1024 + rd0); \
        a[m_][1] = *(const short8*)(p_ + m_ * 1024 + rd1); } \
} while (0)

#define DSB2(bb_, qn_, R_) do { \
    const unsigned short* p_ = &sB[(bb_) * 16384 + ((qn_) * 128 + wn * 32) * 64]; \
    _Pragma("unroll") for (int n_ = 0; n_ < 2; ++n_) { \
        R_[n_][0] = *(const short8*)(p_ + n_ * 1024 + rd0); \
        R_[n_][1] = *(const short8*)(p_ + n_ * 1024 + rd1); } \
} while (0)

// k-outer: 8 independent MFMAs between the two writes of any acc reg.
#define QMF(qm_, qn_, B_) do { \
    _Pragma("unroll") for (int k_ = 0; k_ < 2; ++k_) { \
        _Pragma("unroll") for (int m_ = 0; m_ < 4; ++m_) { \
            _Pragma("unroll") for (int n_ = 0; n_ < 2; ++n_) { \
                acc[qm_][qn_][m_][n_] = __builtin_amdgcn_mfma_f32_16x16x32_bf16(a[m_][k_], B_[n_][k_], acc[qm_][qn_][m_][n_], 0, 0, 0); \
            } } } \
} while (0)

// one barrier per phase; lgkm0 + vmc (ENDOPS) BEFORE it; MFMA after it.
#define PH(DSOPS, STGOPS, MFOPS, ENDOPS) do { \
    DSOPS; \
    STGOPS; \
    SB0; \
    asm volatile("s_waitcnt lgkmcnt(0)" ::: "memory"); \
    ENDOPS; \
    SB0; \
    __builtin_amdgcn_s_barrier(); \
    __builtin_amdgcn_s_setprio(1); \
    MFOPS; \
    __builtin_amdgcn_s_setprio(0); \
    SB0; \
} while (0)

#define ITER8(LDKC, kt0_, SG2, SG3, SG4, SG5, SG6, SG7, SG8, E4, E8) \
    PH(DSA2(0,0); DSB2(0,0,bq0); LGK8, STGA(LDKC,1,1,(kt0_)+1), QMF(0,0,bq0), ); \
    PH(DSB2(0,1,bq1),            SG2,                     QMF(0,1,bq1), ); \
    PH(DSA2(0,1),                SG3,                     QMF(1,0,bq0), ); \
    PH(,                         SG4,                     QMF(1,1,bq1), E4); \
    PH(DSA2(1,0); DSB2(1,0,bq0); LGK8, SG5,               QMF(0,0,bq0), ); \
    PH(DSB2(1,1,bq1),            SG6,                     QMF(0,1,bq1), ); \
    PH(DSA2(1,1),                SG7,                     QMF(1,0,bq0), ); \
    PH(,                         SG8,                     QMF(1,1,bq1), E8);

#define GEMM_PIPE(LDKC, NI_) \
    short8 a[4][2], bq0[2][2], bq1[2][2]; \
    f32x4 acc[2][2][4][2]; \
    _Pragma("unroll") for (int q_ = 0; q_ < 2; ++q_) \
    _Pragma("unroll") for (int r_ = 0; r_ < 2; ++r_) \
    _Pragma("unroll") for (int m_ = 0; m_ < 4; ++m_) \
    _Pragma("unroll") for (int n_ = 0; n_ < 2; ++n_) acc[q_][r_][m_][n_] = (f32x4)0.0f; \
    /* prologue: slots P2..P8 -> b0.Ah0 b0.Bh0 b0.Bh1 b0.Ah1 b1.Ah0 b1.Bh0 b1.Bh1 */ \
    STGA(LDKC,0,0,0); STGB(LDKC,0,0,0); STGB(LDKC,0,1,0); STGA(LDKC,0,1,0); \
    STGA(LDKC,1,0,1); STGB(LDKC,1,0,1); STGB(LDKC,1,1,1); \
    VMC(6); \
    __builtin_amdgcn_s_barrier(); \
    for (int it = 0; it < (NI_) - 1; ++it) { \
        const int kt0 = 2 * it; \
        ITER8(LDKC, kt0, \
              STGA(LDKC,0,0,kt0+2), STGB(LDKC,0,0,kt0+2), STGB(LDKC,0,1,kt0+2), STGA(LDKC,0,1,kt0+2), \
              STGA(LDKC,1,0,kt0+3), STGB(LDKC,1,0,kt0+3), STGB(LDKC,1,1,kt0+3), \
              VMC(6), VMC(6)) \
    } \
    { \
        const int kt0 = 2 * ((NI_) - 1); \
        ITER8(LDKC, kt0, , , , , , , , VMC(0), ) \
    }

// ---------------- GEMM 1: x @ gate_up^T (permuted) + GEGLU, bf16 act out ----------------

__global__ __launch_bounds__(512, 2)
void gemm_gu(const unsigned short* __restrict__ A,    // x bf16 [16384][2048]
             const unsigned short* __restrict__ Bt,   // [E][2816][2048] permuted-transposed
             const float* __restrict__ probs,         // [16384]
             unsigned short* __restrict__ act) {      // [16384][1408] bf16
    __shared__ unsigned short sA[2 * 16384];
    __shared__ unsigned short sB[2 * 16384];
    GEMM_PROLOG(DIM)
    const int bid = blockIdx.x;           // 704 = 8 experts * (8 tm * 11 tn)
    const int e = bid & 7;                // expert per XCD (T1)
    const int local = bid >> 3;           // [0, 88), tm-fastest
    const int tm = local & 7;
    const int tn = local >> 3;            // [0, 11)
    const unsigned short* gA = A  + (size_t)(e * TOK_E + tm * 256) * DIM;
    const unsigned short* gB = Bt + (size_t)e * NGU * DIM + (size_t)(tn * 256) * DIM;

    GEMM_PIPE(DIM, 16)   // K = 2048 = 32 tiles of 64 = 16 iterations

    // epilogue: group g = tn*8 + qn*4 + wn; act col = g*16 + l15
    const int rgrp = lane >> 4;
    #pragma unroll
    for (int qm = 0; qm < 2; ++qm) {
        #pragma unroll
        for (int qn = 0; qn < 2; ++qn) {
            const int acol = tn * 128 + qn * 64 + wn * 16 + l15;
            #pragma unroll
            for (int m = 0; m < 4; ++m) {
                const int row0 = e * TOK_E + tm * 256 + qm * 128 + wm * 64 + m * 16 + rgrp * 4;
                #pragma unroll
                for (int j = 0; j < 4; ++j) {
                    float p = probs[row0 + j];
                    float g = fminf(acc[qm][qn][m][0][j], 7.0f);
                    float u = fminf(fmaxf(acc[qm][qn][m][1][j], -7.0f), 7.0f);
                    float glu = g / (1.0f + __expf(-1.702f * g));
                    float r = glu * (u + 1.0f) * p;
                    act[(size_t)(row0 + j) * INTER + acol] = f2bf(r);
                }
            }
        }
    }
}

// ---------------- GEMM 2: act @ down^T, fp32 out ----------------

__global__ __launch_bounds__(512, 2)
void gemm_down(const unsigned short* __restrict__ A,   // act bf16 [16384][1408]
               const unsigned short* __restrict__ Bt,  // [E][2048][1408]
               float* __restrict__ out) {               // [16384][2048] fp32
    __shared__ unsigned short sA[2 * 16384];
    __shared__ unsigned short sB[2 * 16384];
    GEMM_PROLOG(INTER)
    const int bid = blockIdx.x;           // 512 = 8 experts * (8 tm * 8 tn)
    const int e = bid & 7;
    const int local = bid >> 3;           // [0, 64), tm-fastest
    const int tm = local & 7;
    const int tn = local >> 3;            // [0, 8)
    const unsigned short* gA = A  + (size_t)(e * TOK_E + tm * 256) * INTER;
    const unsigned short* gB = Bt + (size_t)e * DIM * INTER + (size_t)(tn * 256) * INTER;

    GEMM_PIPE(INTER, 11)   // K = 1408 = 22 tiles of 64 = 11 iterations

    const int rgrp = lane >> 4;
    #pragma unroll
    for (int qm = 0; qm < 2; ++qm) {
        #pragma unroll
        for (int qn = 0; qn < 2; ++qn) {
            #pragma unroll
            for (int m = 0; m < 4; ++m) {
                const int row0 = e * TOK_E + tm * 256 + qm * 128 + wm * 64 + m * 16 + rgrp * 4;
                #pragma unroll
                for (int j = 0; j < 4; ++j) {
                    #pragma unroll
                    for (int n = 0; n < 2; ++n) {
                        const int col = tn * 256 + qn * 128 + wn * 32 + n * 16 + l15;
                        out[(size_t)(row0 + j) * DIM + col] = acc[qm][qn][m][n][j];
                    }
                }
            }
        }
    }
}

// ---------------- launcher ----------------

extern "C" void kernel_launch(void* const* d_in, const int* in_sizes, int n_in,
                              void* d_out, int out_size, void* d_ws, size_t ws_size,
                              hipStream_t stream) {
    const float* x     = (const float*)d_in[0];
    const float* probs = (const float*)d_in[1];
    const float* gup   = (const float*)d_in[2];
    const float* dwn   = (const float*)d_in[3];
    float* out = (float*)d_out;

    char* ws = (char*)d_ws;
    const size_t SZ_XB  = (size_t)TOTAL_TOKENS * DIM * 2;      // 67,108,864
    const size_t SZ_GUB = (size_t)N_EXPERTS * NGU * DIM * 2;   // 92,274,688
    const size_t SZ_DWB = (size_t)N_EXPERTS * DIM * INTER * 2; // 46,137,344
    unsigned short* xb   = (unsigned short*)(ws);
    unsigned short* gub  = (unsigned short*)(ws + SZ_XB);
    unsigned short* dwb  = (unsigned short*)(ws + SZ_XB + SZ_GUB);
    unsigned short* actb = (unsigned short*)(ws + SZ_XB + SZ_GUB + SZ_DWB);

    convert_x<<<2048, 256, 0, stream>>>(x, xb, TOTAL_TOKENS * DIM / 8);

    dim3 tg(NGU / 32, DIM / 128, 16);             // (88, 16, 16); z>=8 uses (64, 11)
    transpose_convert2<<<tg, 256, 0, stream>>>(gup, gub, dwn, dwb);

    gemm_gu<<<704, 512, 0, stream>>>(xb, gub, probs, actb);
    gemm_down<<<512, 512, 0, stream>>>(actb, dwb, out);
}